// Round 11
// baseline (481.983 us; speedup 1.0000x reference)
//
#include <hip/hip_runtime.h>
#include <stdint.h>

#define NN 10000
#define NE 160000
// C=64, M=9, H=8, D=8, RH=64, WN=192

struct BF16 { unsigned short v; };
typedef _Float16 h2_t __attribute__((ext_vector_type(2)));
typedef _Float16 f16x8 __attribute__((ext_vector_type(8)));
typedef float f32x4 __attribute__((ext_vector_type(4)));

__device__ __forceinline__ float cvt(float x) { return x; }
__device__ __forceinline__ float cvt(BF16 x) {
    union { unsigned int i; float f; } u; u.i = ((unsigned int)x.v) << 16; return u.f;
}
__device__ __forceinline__ unsigned short f2b_us(float f) {
    union { float f; unsigned int i; } v; v.f = f;
    unsigned int x = v.i;
    unsigned int lsb = (x >> 16) & 1u;
    x += 0x7fffu + lsb;
    return (unsigned short)(x >> 16);
}
__device__ __forceinline__ float rlane(float v, int l) {
    return __uint_as_float((unsigned int)__builtin_amdgcn_readlane(__float_as_uint(v), l));
}
__device__ __forceinline__ h2_t rlane_pk(h2_t v, int l) {
    union { h2_t h; unsigned int u; } c; c.h = v;
    c.u = (unsigned int)__builtin_amdgcn_readlane(c.u, l);
    return c.h;
}
__device__ __forceinline__ h2_t pkh2(float a, float b) {
    h2_t r; r[0] = (_Float16)a; r[1] = (_Float16)b; return r;
}
__device__ __forceinline__ float fdot2f(h2_t a, h2_t b, float c) {
#if __has_builtin(__builtin_amdgcn_fdot2)
    return __builtin_amdgcn_fdot2(a, b, c, false);
#else
    return fmaf((float)a[0], (float)b[0], fmaf((float)a[1], (float)b[1], c));
#endif
}
__device__ __forceinline__ float sigm(float x) { return 1.0f / (1.0f + __expf(-x)); }
__device__ __forceinline__ int clampi(int v, int hi) { return (unsigned)v >= (unsigned)hi ? 0 : v; }

__device__ __forceinline__ void stOut(float* p, size_t i, float v) { p[i] = v; }
__device__ __forceinline__ void stOut(unsigned short* p, size_t i, float v) { p[i] = f2b_us(v); }

// ordered-uint encoding for float atomicMax
__device__ __forceinline__ unsigned okey(float f) {
    unsigned b = __float_as_uint(f);
    return (b & 0x80000000u) ? ~b : (b | 0x80000000u);
}
__device__ __forceinline__ float okdec(unsigned k) {
    unsigned b = (k & 0x80000000u) ? (k ^ 0x80000000u) : ~k;
    return __uint_as_float(b);
}

// 8 consecutive elements of T -> f16x8 (vector loads)
__device__ __forceinline__ f16x8 ld8f16(const BF16* p) {
    uint4 v = *(const uint4*)p;
    unsigned w0 = v.x, w1 = v.y, w2 = v.z, w3 = v.w;
    f16x8 r;
    union { unsigned u; float f; } c;
    c.u = (w0 & 0xFFFFu) << 16;  r[0] = (_Float16)c.f;
    c.u = (w0 & 0xFFFF0000u);    r[1] = (_Float16)c.f;
    c.u = (w1 & 0xFFFFu) << 16;  r[2] = (_Float16)c.f;
    c.u = (w1 & 0xFFFF0000u);    r[3] = (_Float16)c.f;
    c.u = (w2 & 0xFFFFu) << 16;  r[4] = (_Float16)c.f;
    c.u = (w2 & 0xFFFF0000u);    r[5] = (_Float16)c.f;
    c.u = (w3 & 0xFFFFu) << 16;  r[6] = (_Float16)c.f;
    c.u = (w3 & 0xFFFF0000u);    r[7] = (_Float16)c.f;
    return r;
}
__device__ __forceinline__ f16x8 ld8f16(const float* p) {
    float4 a = *(const float4*)p;
    float4 b = *(const float4*)(p + 4);
    f16x8 r;
    r[0] = (_Float16)a.x; r[1] = (_Float16)a.y; r[2] = (_Float16)a.z; r[3] = (_Float16)a.w;
    r[4] = (_Float16)b.x; r[5] = (_Float16)b.y; r[6] = (_Float16)b.z; r[7] = (_Float16)b.w;
    return r;
}

// ---------------- K0: zero cnt + csr + nsum32 + mseg + sseg, probe dtype, set flag ----------------
// Block 0 is the sole flag writer (probe folded in; no cross-block race).
__global__ void k0_zero(int* __restrict__ cnt, int* __restrict__ csr, int* __restrict__ flag,
                        float* __restrict__ nsum, unsigned* __restrict__ mseg,
                        float* __restrict__ sseg, const unsigned short* __restrict__ x) {
    int i = blockIdx.x * blockDim.x + threadIdx.x;
    if (blockIdx.x == 0) {
        __shared__ int sbad[256];
        int bad = 0;
        for (int j = threadIdx.x; j < 16384; j += blockDim.x) {
            unsigned e = (x[j] >> 7) & 0xFFu;
            bad += (e == 0xFFu);
        }
        sbad[threadIdx.x] = bad;
        __syncthreads();
        for (int o = 128; o >= 1; o >>= 1) {
            if (threadIdx.x < o) sbad[threadIdx.x] += sbad[threadIdx.x + o];
            __syncthreads();
        }
        if (threadIdx.x == 0) *flag = (sbad[0] > 0) ? 0 : 1;   // bf16 world iff no 0xFF exponents
    }
    if (i < NN) cnt[i] = 0;
    if (i < NE) csr[i] = 0;
    if (i < NN * 8) { mseg[i] = 0u; sseg[i] = 0.f; }
    for (int j = i; j < NN * 576; j += gridDim.x * blockDim.x) nsum[j] = 0.f;
}

// ---------------- K1m: MFMA node feats -> fs, fd ----------------
template<typename T>
__device__ void k1m_body(const T* x, const T* Ws, const T* bs, const T* Wd,
                         _Float16* fs, _Float16* fd, _Float16 (*Yt)[128])
{
    const int lane = threadIdx.x & 63;
    const int c16 = lane & 15;
    const int kg  = lane >> 4;

    f16x8 bWs[4][2], bWd[4][2];
#pragma unroll
    for (int t = 0; t < 4; t++)
#pragma unroll
        for (int kh = 0; kh < 2; kh++) {
            f16x8 f1, f2;
#pragma unroll
            for (int j = 0; j < 8; j++) {
                int k = kh * 32 + kg * 8 + j;
                f1[j] = (_Float16)cvt(Ws[(size_t)k * 64 + t * 16 + c16]);
                f2[j] = (_Float16)cvt(Wd[(size_t)k * 64 + t * 16 + c16]);
            }
            bWs[t][kh] = f1; bWd[t][kh] = f2;
        }
    float bsv[4];
#pragma unroll
    for (int t = 0; t < 4; t++) bsv[t] = cvt(bs[t * 16 + c16]);

    const int NT = (NN * 9) / 16;   // 5625 exact
    for (int tile = blockIdx.x * 4 + (threadIdx.x >> 6); tile < NT; tile += gridDim.x * 4) {
        const int r0 = tile * 16;
        f16x8 a0 = ld8f16(&x[(size_t)(r0 + c16) * 64 + kg * 8]);
        f16x8 a1 = ld8f16(&x[(size_t)(r0 + c16) * 64 + 32 + kg * 8]);
        f32x4 hs[4] = {{0,0,0,0},{0,0,0,0},{0,0,0,0},{0,0,0,0}};
        f32x4 hd[4] = {{0,0,0,0},{0,0,0,0},{0,0,0,0},{0,0,0,0}};
#pragma unroll
        for (int t = 0; t < 4; t++) {
            hs[t] = __builtin_amdgcn_mfma_f32_16x16x32_f16(a0, bWs[t][0], hs[t], 0, 0, 0);
            hs[t] = __builtin_amdgcn_mfma_f32_16x16x32_f16(a1, bWs[t][1], hs[t], 0, 0, 0);
            hd[t] = __builtin_amdgcn_mfma_f32_16x16x32_f16(a0, bWd[t][0], hd[t], 0, 0, 0);
            hd[t] = __builtin_amdgcn_mfma_f32_16x16x32_f16(a1, bWd[t][1], hd[t], 0, 0, 0);
        }
#pragma unroll
        for (int t = 0; t < 4; t++)
#pragma unroll
            for (int r = 0; r < 4; r++) {
                int row = kg * 4 + r;
                float vs = hs[t][r];
                if (((r0 + row) % 9) == 0) vs += bsv[t];
                Yt[row][t * 16 + c16] = (_Float16)vs;
                Yt[row][64 + t * 16 + c16] = (_Float16)hd[t][r];
            }
#pragma unroll
        for (int j = 0; j < 2; j++) {
            int c = lane + 64 * j;      // chunk 0..127
            int row = c >> 3;
            int cc = (c & 7) * 8;
            *(f16x8*)&fs[(size_t)(r0 + row) * 64 + cc] = *(const f16x8*)&Yt[row][cc];
            *(f16x8*)&fd[(size_t)(r0 + row) * 64 + cc] = *(const f16x8*)&Yt[row][64 + cc];
        }
    }
}

__global__ __launch_bounds__(256) void k1m_feats(
    const void* x, const void* Ws, const void* bs, const void* Wd,
    _Float16* fs, _Float16* fd, const int* flag)
{
    __shared__ _Float16 Y[4][16][128];   // 16 KB
    const int wv = threadIdx.x >> 6;
    if (*flag) k1m_body<BF16>((const BF16*)x, (const BF16*)Ws, (const BF16*)bs, (const BF16*)Wd,
                              fs, fd, Y[wv]);
    else       k1m_body<float>((const float*)x, (const float*)Ws, (const float*)bs, (const float*)Wd,
                               fs, fd, Y[wv]);
}

// ---------------- K2: CSR build ----------------
__global__ void k2a_count(const int* __restrict__ dst, int* __restrict__ cnt) {
    for (int e = blockIdx.x * blockDim.x + threadIdx.x; e < NE; e += gridDim.x * blockDim.x)
        atomicAdd(&cnt[clampi(dst[e], NN)], 1);
}

__global__ __launch_bounds__(1024) void k2b_scan(const int* __restrict__ cnt,
                                                 int* __restrict__ off, int* __restrict__ cur) {
    __shared__ int part[1024];
    int t = threadIdx.x;
    int base = t * 10;
    int loc[10]; int s = 0;
#pragma unroll
    for (int k = 0; k < 10; k++) { int i = base + k; int v = (i < NN) ? cnt[i] : 0; loc[k] = v; s += v; }
    part[t] = s; __syncthreads();
    for (int o = 1; o < 1024; o <<= 1) {
        int v = (t >= o) ? part[t - o] : 0;
        __syncthreads();
        part[t] += v;
        __syncthreads();
    }
    int run = (t == 0) ? 0 : part[t - 1];
#pragma unroll
    for (int k = 0; k < 10; k++) {
        int i = base + k;
        if (i < NN) { off[i] = run; cur[i] = run; run += loc[k]; }
    }
    if (t == 1023) off[NN] = part[1023];
}

__global__ void k2c_fill(const int* __restrict__ dst, int* __restrict__ cur, int* __restrict__ csr) {
    for (int e = blockIdx.x * blockDim.x + threadIdx.x; e < NE; e += gridDim.x * blockDim.x) {
        int d = clampi(dst[e], NN);
        int p = atomicAdd(&cur[d], 1);
        if ((unsigned)p < (unsigned)NE) csr[p] = e;
    }
}

// ---------------- K3m: MFMA radial MLP -> wlc f16 [E][3][64] ----------------
template<typename T>
__device__ void k3m_body(const T* es, const T* W1, const T* b1g, const T* gg, const T* bbv,
                         const T* W2, const T* roff, _Float16* wlc,
                         _Float16 (*Yt)[200])
{
    const int lane = threadIdx.x & 63;
    const int c16 = lane & 15;
    const int kg  = lane >> 4;

    f16x8 bW1[4][2], bW2[12][2];
#pragma unroll
    for (int t = 0; t < 4; t++)
#pragma unroll
        for (int kh = 0; kh < 2; kh++) {
            f16x8 f;
#pragma unroll
            for (int j = 0; j < 8; j++) {
                int k = kh * 32 + kg * 8 + j;
                f[j] = (_Float16)cvt(W1[(size_t)k * 64 + t * 16 + c16]);
            }
            bW1[t][kh] = f;
        }
#pragma unroll
    for (int t = 0; t < 12; t++)
#pragma unroll
        for (int kh = 0; kh < 2; kh++) {
            f16x8 f;
#pragma unroll
            for (int j = 0; j < 8; j++) {
                int k = kh * 32 + kg * 8 + j;
                f[j] = (_Float16)cvt(W2[(size_t)k * 192 + t * 16 + c16]);
            }
            bW2[t][kh] = f;
        }
    float b1v[4], gv[4], bv[4], rv[12];
#pragma unroll
    for (int t = 0; t < 4; t++) {
        b1v[t] = cvt(b1g[t * 16 + c16]);
        gv[t]  = cvt(gg[t * 16 + c16]);
        bv[t]  = cvt(bbv[t * 16 + c16]);
    }
#pragma unroll
    for (int t = 0; t < 12; t++) rv[t] = cvt(roff[t * 16 + c16]);

    const int NT = NE / 16;   // 10000 exact
    for (int tile = blockIdx.x * 4 + (threadIdx.x >> 6); tile < NT; tile += gridDim.x * 4) {
        const int e0 = tile * 16;
        f16x8 a0 = ld8f16(&es[(size_t)(e0 + c16) * 64 + kg * 8]);
        f16x8 a1 = ld8f16(&es[(size_t)(e0 + c16) * 64 + 32 + kg * 8]);
        f32x4 h[4] = {{0,0,0,0},{0,0,0,0},{0,0,0,0},{0,0,0,0}};
#pragma unroll
        for (int t = 0; t < 4; t++) {
            h[t] = __builtin_amdgcn_mfma_f32_16x16x32_f16(a0, bW1[t][0], h[t], 0, 0, 0);
            h[t] = __builtin_amdgcn_mfma_f32_16x16x32_f16(a1, bW1[t][1], h[t], 0, 0, 0);
        }
#pragma unroll
        for (int r = 0; r < 4; r++) {
            float x0 = h[0][r] + b1v[0], x1 = h[1][r] + b1v[1];
            float x2 = h[2][r] + b1v[2], x3 = h[3][r] + b1v[3];
            float s = x0 + x1 + x2 + x3;
            float q = x0 * x0 + x1 * x1 + x2 * x2 + x3 * x3;
            s += __shfl_xor(s, 1, 64); q += __shfl_xor(q, 1, 64);
            s += __shfl_xor(s, 2, 64); q += __shfl_xor(q, 2, 64);
            s += __shfl_xor(s, 4, 64); q += __shfl_xor(q, 4, 64);
            s += __shfl_xor(s, 8, 64); q += __shfl_xor(q, 8, 64);
            float mu = s * (1.0f / 64.0f);
            float var = fmaxf(q * (1.0f / 64.0f) - mu * mu, 0.0f);
            float rs = rsqrtf(var + 1e-5f);
            int row = kg * 4 + r;
#pragma unroll
            for (int t = 0; t < 4; t++) {
                float xt = (t == 0) ? x0 : (t == 1) ? x1 : (t == 2) ? x2 : x3;
                float v = (xt - mu) * rs * gv[t] + bv[t];
                v = v * sigm(v);
                Yt[row][t * 16 + c16] = (_Float16)v;
            }
        }
        f16x8 a20 = *(const f16x8*)&Yt[c16][kg * 8];
        f16x8 a21 = *(const f16x8*)&Yt[c16][32 + kg * 8];
        f32x4 y[12] = {{0,0,0,0},{0,0,0,0},{0,0,0,0},{0,0,0,0},{0,0,0,0},{0,0,0,0},
                       {0,0,0,0},{0,0,0,0},{0,0,0,0},{0,0,0,0},{0,0,0,0},{0,0,0,0}};
#pragma unroll
        for (int t = 0; t < 12; t++) {
            y[t] = __builtin_amdgcn_mfma_f32_16x16x32_f16(a20, bW2[t][0], y[t], 0, 0, 0);
            y[t] = __builtin_amdgcn_mfma_f32_16x16x32_f16(a21, bW2[t][1], y[t], 0, 0, 0);
        }
#pragma unroll
        for (int t = 0; t < 12; t++)
#pragma unroll
            for (int r = 0; r < 4; r++)
                Yt[kg * 4 + r][t * 16 + c16] = (_Float16)(y[t][r] + rv[t]);
#pragma unroll
        for (int j = 0; j < 6; j++) {
            int c = lane + 64 * j;
            int row = c / 24;
            int cc = (c % 24) * 8;
            *(f16x8*)&wlc[(size_t)(e0 + row) * 192 + cc] = *(const f16x8*)&Yt[row][cc];
        }
    }
}

__global__ __launch_bounds__(256) void k3m_wlc(
    const void* es, const void* W1, const void* b1, const void* g, const void* bln,
    const void* W2, const void* roff, _Float16* wlc, const int* flag)
{
    __shared__ _Float16 Y[4][16][200];   // 25.6 KB
    const int wv = threadIdx.x >> 6;
    if (*flag) k3m_body<BF16>((const BF16*)es, (const BF16*)W1, (const BF16*)b1, (const BF16*)g,
                              (const BF16*)bln, (const BF16*)W2, (const BF16*)roff, wlc, Y[wv]);
    else       k3m_body<float>((const float*)es, (const float*)W1, (const float*)b1, (const float*)g,
                               (const float*)bln, (const float*)W2, (const float*)roff, wlc, Y[wv]);
}

// ---------------- K4m: MFMA alpha logits + segment atomicMax ----------------
template<typename T>
__device__ void k4m_body(const T* ea, const _Float16* fs, const _Float16* fd,
                         const _Float16* wlc, const T* Wa, const T* ba, const T* adot,
                         const int* esrc, const int* edst, float* alpha, unsigned* mseg,
                         float (*aS)[8])
{
    const int lane = threadIdx.x & 63;
    const int c16 = lane & 15;
    const int kgr = lane >> 4;

    f16x8 bWa[4][2];
#pragma unroll
    for (int t = 0; t < 4; t++)
#pragma unroll
        for (int kh = 0; kh < 2; kh++) {
            f16x8 f;
#pragma unroll
            for (int j = 0; j < 8; j++) {
                int k = kh * 32 + kgr * 8 + j;
                f[j] = (_Float16)cvt(Wa[(size_t)k * 64 + t * 16 + c16]);
            }
            bWa[t][kh] = f;
        }
    float bav[4], adv[4];
#pragma unroll
    for (int t = 0; t < 4; t++) {
        bav[t] = cvt(ba[t * 16 + c16]);
        adv[t] = cvt(adot[t * 16 + c16]);
    }

    const int NT = NE / 16;   // 10000 exact
    for (int tile = blockIdx.x * 4 + (threadIdx.x >> 6); tile < NT; tile += gridDim.x * 4) {
        const int e0 = tile * 16;
        const int eA = e0 + c16;
        const int sn = clampi(esrc[eA], NN);
        const int dn = clampi(edst[eA], NN);
        f16x8 fs0 = *(const f16x8*)&fs[(size_t)sn * 576 + kgr * 8];
        f16x8 fs1 = *(const f16x8*)&fs[(size_t)sn * 576 + 32 + kgr * 8];
        f16x8 fd0 = *(const f16x8*)&fd[(size_t)dn * 576 + kgr * 8];
        f16x8 fd1 = *(const f16x8*)&fd[(size_t)dn * 576 + 32 + kgr * 8];
        f16x8 wl0 = *(const f16x8*)&wlc[(size_t)eA * 192 + kgr * 8];
        f16x8 wl1 = *(const f16x8*)&wlc[(size_t)eA * 192 + 32 + kgr * 8];
        _Float16 eh = (_Float16)cvt(ea[(size_t)eA * 9]);
        f16x8 ev;
#pragma unroll
        for (int j = 0; j < 8; j++) ev[j] = eh;
        f16x8 a0 = (fs0 + fd0) * ev * wl0;
        f16x8 a1 = (fs1 + fd1) * ev * wl1;

        f32x4 d[4] = {{0,0,0,0},{0,0,0,0},{0,0,0,0},{0,0,0,0}};
#pragma unroll
        for (int t = 0; t < 4; t++) {
            d[t] = __builtin_amdgcn_mfma_f32_16x16x32_f16(a0, bWa[t][0], d[t], 0, 0, 0);
            d[t] = __builtin_amdgcn_mfma_f32_16x16x32_f16(a1, bWa[t][1], d[t], 0, 0, 0);
        }
#pragma unroll
        for (int t = 0; t < 4; t++)
#pragma unroll
            for (int r = 0; r < 4; r++) {
                float aw = d[t][r] + bav[t];
                float f = aw * (0.2f + 0.8f * sigm(aw));   // smooth_lrelu
                float p = f * adv[t];
                p += __shfl_xor(p, 1, 64);
                p += __shfl_xor(p, 2, 64);
                p += __shfl_xor(p, 4, 64);
                if ((c16 & 7) == 0)
                    aS[kgr * 4 + r][t * 2 + (c16 >> 3)] = p;
            }
        // coalesced alpha store + distributed atomicMax (2 entries/lane)
#pragma unroll
        for (int j = 0; j < 2; j++) {
            int idx = lane * 2 + j;       // 0..127
            int row = idx >> 3, h = idx & 7;
            float p = aS[row][h];
            alpha[(size_t)(e0 + row) * 8 + h] = p;
            int dnr = clampi(edst[e0 + row], NN);
            atomicMax(&mseg[dnr * 8 + h], okey(p));
        }
    }
}

__global__ __launch_bounds__(256) void k4m_alpha(
    const void* ea, const _Float16* fs, const _Float16* fd, const _Float16* wlc,
    const void* Wa, const void* ba, const void* adot,
    const int* esrc, const int* edst, float* alpha, unsigned* mseg, const int* flag)
{
    __shared__ float A[4][16][8];   // 2 KB
    const int wv = threadIdx.x >> 6;
    if (*flag) k4m_body<BF16>((const BF16*)ea, fs, fd, wlc, (const BF16*)Wa, (const BF16*)ba,
                              (const BF16*)adot, esrc, edst, alpha, mseg, A[wv]);
    else       k4m_body<float>((const float*)ea, fs, fd, wlc, (const float*)Wa, (const float*)ba,
                               (const float*)adot, esrc, edst, alpha, mseg, A[wv]);
}

// ---------------- K5b: edge-parallel exp + segment sum ----------------
__global__ void k5b_expsum(const int* __restrict__ edst, const unsigned* __restrict__ mseg,
                           float* __restrict__ alpha, float* __restrict__ sseg) {
    int t = blockIdx.x * blockDim.x + threadIdx.x;
    if (t >= NE * 8) return;
    int e = t >> 3, h = t & 7;
    int dn = clampi(edst[e], NN);
    float m = okdec(mseg[dn * 8 + h]);
    float ex = __expf(alpha[t] - m);
    alpha[t] = ex;
    unsafeAtomicAdd(&sseg[dn * 8 + h], ex);
}

// ---------------- K6m v2.1: MFMA msg+value+gate+cp_tp, 2 waves/node, LDS staging ----------------
// 4 nodes per wave (grid 1250): stride gridDim*4 is even so half=gw&1 is wave-invariant
// and the B-fragment prologue hoists out of the node loop (amortized 4x). 108 VGPR preserved.
template<typename T>
__device__ void k6m_body(const int* off, const int* csr, const int* esrc,
                         const T* ea, const _Float16* fs, const _Float16* fd,
                         const _Float16* wlc, const T* Wv, const T* bv,
                         const float* alpha, const float* sseg, float* nsum,
                         _Float16 (*wlS)[16][72], float (*mtS)[20])
{
    const int lane = threadIdx.x & 63;
    const int wvid = threadIdx.x >> 6;
    const int c16 = lane & 15;     // A row / D col (within 16-tile)
    const int kg  = lane >> 4;     // k-group & D row-group

    const int gw0  = blockIdx.x * 4 + wvid;
    const int half = gw0 & 1;      // invariant across the gw loop (stride even)

    // ---- B fragments for this wave's two 16-col tiles (hoisted: half is wave-invariant) ----
    f16x8 bfV[2][2], bfG[2][2];
    float bvv[2], bgv[2];
    int colg[2], hh[2];
#pragma unroll
    for (int t = 0; t < 2; t++) {
        colg[t] = (half * 2 + t) * 16 + c16;
        hh[t] = colg[t] >> 3;
#pragma unroll
        for (int kh = 0; kh < 2; kh++) {
            f16x8 b8v, b8g;
#pragma unroll
            for (int j = 0; j < 8; j++) {
                int k = kh * 32 + kg * 8 + j;
                b8v[j] = (_Float16)cvt(Wv[(size_t)k * 128 + colg[t]]);
                b8g[j] = (_Float16)cvt(Wv[(size_t)k * 128 + 64 + colg[t]]);
            }
            bfV[t][kh] = b8v; bfG[t][kh] = b8g;
        }
        bvv[t] = cvt(bv[colg[t]]);
        bgv[t] = cvt(bv[64 + colg[t]]);
    }

    for (int gw = gw0; gw < NN * 2; gw += gridDim.x * 4) {
        const int n = gw >> 1;
        const int b = off[n], e_end = off[n + 1];
        if (b >= e_end) continue;

        float invs[2];
        invs[0] = 1.0f / (sseg[n * 8 + hh[0]] + 1e-16f);
        invs[1] = 1.0f / (sseg[n * 8 + hh[1]] + 1e-16f);

        const size_t fdb = (size_t)n * 576;
        const size_t nbase = (size_t)n * 576;

        for (int p0 = b; p0 < e_end; p0 += 16) {
            int pA = p0 + c16; if (pA >= e_end) pA = e_end - 1;
            const int eA = clampi(csr[pA], NE);
            const int snA = clampi(esrc[eA], NN);
            const size_t fsb = (size_t)snA * 576;
            const size_t wlb = (size_t)eA * 192;

            // ---- stage wl rows (raw f16), ea row, alpha row into LDS ----
#pragma unroll
            for (int l = 0; l < 3; l++)
#pragma unroll
                for (int kh = 0; kh < 2; kh++)
                    *(f16x8*)&wlS[l][c16][kh * 32 + kg * 8] =
                        *(const f16x8*)&wlc[wlb + (size_t)l * 64 + kh * 32 + kg * 8];
            float eao[9];
#pragma unroll
            for (int m = 0; m < 9; m++) eao[m] = cvt(ea[(size_t)eA * 9 + m]);
            if (kg == 0) {
#pragma unroll
                for (int m = 0; m < 9; m++) mtS[c16][m] = eao[m];
            }
            mtS[c16][10 + kg * 2]     = alpha[(size_t)eA * 8 + kg * 2];
            mtS[c16][10 + kg * 2 + 1] = alpha[(size_t)eA * 8 + kg * 2 + 1];

            // per-epilogue-row alpha * invs * validity (m-independent)
            float awm[2][4];
#pragma unroll
            for (int r = 0; r < 4; r++) {
                int row = kg * 4 + r;
                float vm = (p0 + row < e_end) ? 1.f : 0.f;
#pragma unroll
                for (int t = 0; t < 2; t++)
                    awm[t][r] = mtS[row][10 + hh[t]] * invs[t] * vm;
            }

            float gtv[2][4];
            // ---------- m = 0: value + gate ----------
            {
                f16x8 a0, a1;
                {
                    f16x8 w0 = *(const f16x8*)&wlS[0][c16][kg * 8];
                    f16x8 w1 = *(const f16x8*)&wlS[0][c16][32 + kg * 8];
                    f16x8 fd0 = *(const f16x8*)&fd[fdb + kg * 8];
                    f16x8 fd1 = *(const f16x8*)&fd[fdb + 32 + kg * 8];
                    f16x8 fs0 = *(const f16x8*)&fs[fsb + kg * 8];
                    f16x8 fs1 = *(const f16x8*)&fs[fsb + 32 + kg * 8];
                    _Float16 eh = (_Float16)eao[0];
                    f16x8 ev;
#pragma unroll
                    for (int j = 0; j < 8; j++) ev[j] = eh;
                    a0 = (fs0 + fd0) * ev * w0;
                    a1 = (fs1 + fd1) * ev * w1;
                }
                f32x4 d[2] = {{0,0,0,0},{0,0,0,0}};
                f32x4 g[2] = {{0,0,0,0},{0,0,0,0}};
#pragma unroll
                for (int t = 0; t < 2; t++) {
                    d[t] = __builtin_amdgcn_mfma_f32_16x16x32_f16(a0, bfV[t][0], d[t], 0, 0, 0);
                    d[t] = __builtin_amdgcn_mfma_f32_16x16x32_f16(a1, bfV[t][1], d[t], 0, 0, 0);
                    g[t] = __builtin_amdgcn_mfma_f32_16x16x32_f16(a0, bfG[t][0], g[t], 0, 0, 0);
                    g[t] = __builtin_amdgcn_mfma_f32_16x16x32_f16(a1, bfG[t][1], g[t], 0, 0, 0);
                }
#pragma unroll
                for (int t = 0; t < 2; t++) {
                    float ps = 0.f;
#pragma unroll
                    for (int r = 0; r < 4; r++) {
                        int row = kg * 4 + r;
                        gtv[t][r] = sigm(g[t][r] + bgv[t]);
                        float v = d[t][r] + bvv[t];
                        float f = v * sigm(v);
                        float wlv = (float)wlS[0][row][colg[t]];
                        float eam = mtS[row][0];
                        ps = fmaf(f * (eam * wlv), awm[t][r], ps);
                    }
                    ps += __shfl_xor(ps, 16, 64);
                    ps += __shfl_xor(ps, 32, 64);
                    if (kg == 0) unsafeAtomicAdd(&nsum[nbase + colg[t]], ps);
                }
            }
            // ---------- m = 1..8: value * gate ----------
#pragma unroll 2
            for (int m = 1; m < 9; m++) {
                const int l = (m < 4) ? 1 : 2;
                f16x8 a0, a1;
                {
                    const size_t mo = (size_t)m * 64;
                    f16x8 w0 = *(const f16x8*)&wlS[l][c16][kg * 8];
                    f16x8 w1 = *(const f16x8*)&wlS[l][c16][32 + kg * 8];
                    f16x8 fd0 = *(const f16x8*)&fd[fdb + mo + kg * 8];
                    f16x8 fd1 = *(const f16x8*)&fd[fdb + mo + 32 + kg * 8];
                    f16x8 fs0 = *(const f16x8*)&fs[fsb + mo + kg * 8];
                    f16x8 fs1 = *(const f16x8*)&fs[fsb + mo + 32 + kg * 8];
                    _Float16 eh = (_Float16)eao[m];
                    f16x8 ev;
#pragma unroll
                    for (int j = 0; j < 8; j++) ev[j] = eh;
                    a0 = (fs0 + fd0) * ev * w0;
                    a1 = (fs1 + fd1) * ev * w1;
                }
                f32x4 d[2] = {{0,0,0,0},{0,0,0,0}};
#pragma unroll
                for (int t = 0; t < 2; t++) {
                    d[t] = __builtin_amdgcn_mfma_f32_16x16x32_f16(a0, bfV[t][0], d[t], 0, 0, 0);
                    d[t] = __builtin_amdgcn_mfma_f32_16x16x32_f16(a1, bfV[t][1], d[t], 0, 0, 0);
                }
#pragma unroll
                for (int t = 0; t < 2; t++) {
                    float ps = 0.f;
#pragma unroll
                    for (int r = 0; r < 4; r++) {
                        int row = kg * 4 + r;
                        float f = d[t][r] * gtv[t][r];
                        float wlv = (float)wlS[l][row][colg[t]];
                        float eam = mtS[row][m];
                        ps = fmaf(f * (eam * wlv), awm[t][r], ps);
                    }
                    ps += __shfl_xor(ps, 16, 64);
                    ps += __shfl_xor(ps, 32, 64);
                    if (kg == 0) unsafeAtomicAdd(&nsum[nbase + (size_t)m * 64 + colg[t]], ps);
                }
            }
        }
    }
}

__global__ __launch_bounds__(256) void k6m_fused(
    const int* off, const int* csr, const int* esrc,
    const void* ea, const _Float16* fs, const _Float16* fd, const _Float16* wlc,
    const void* Wv, const void* bv,
    const float* alpha, const float* sseg, float* nsum, const int* flag)
{
    __shared__ _Float16 shwl[4][3][16][72];   // 27.0 KB
    __shared__ float    shmt[4][16][20];      //  5.0 KB
    const int wvid = threadIdx.x >> 6;
    if (*flag) k6m_body<BF16>(off, csr, esrc, (const BF16*)ea, fs, fd, wlc,
                              (const BF16*)Wv, (const BF16*)bv, alpha, sseg, nsum,
                              shwl[wvid], shmt[wvid]);
    else       k6m_body<float>(off, csr, esrc, (const float*)ea, fs, fd, wlc,
                               (const float*)Wv, (const float*)bv, alpha, sseg, nsum,
                               shwl[wvid], shmt[wvid]);
}

// ---------------- K7m: MFMA output projection (f32 nsum -> out) ----------------
template<typename T, typename OT>
__device__ void k7m_body(const float* ns, const T* Wp, const T* bp, OT* out, OT (*Yt)[72])
{
    const int lane = threadIdx.x & 63;
    const int c16 = lane & 15;
    const int kg  = lane >> 4;

    f16x8 bWp[4][2];
#pragma unroll
    for (int t = 0; t < 4; t++)
#pragma unroll
        for (int kh = 0; kh < 2; kh++) {
            f16x8 f;
#pragma unroll
            for (int j = 0; j < 8; j++) {
                int k = kh * 32 + kg * 8 + j;
                f[j] = (_Float16)cvt(Wp[(size_t)k * 64 + t * 16 + c16]);
            }
            bWp[t][kh] = f;
        }
    float bpv[4];
#pragma unroll
    for (int t = 0; t < 4; t++) bpv[t] = cvt(bp[t * 16 + c16]);

    const int NT = (NN * 9) / 16;   // 5625 exact
    for (int tile = blockIdx.x * 4 + (threadIdx.x >> 6); tile < NT; tile += gridDim.x * 4) {
        const int r0 = tile * 16;
        f16x8 a0 = ld8f16(&ns[(size_t)(r0 + c16) * 64 + kg * 8]);
        f16x8 a1 = ld8f16(&ns[(size_t)(r0 + c16) * 64 + 32 + kg * 8]);
        f32x4 d[4] = {{0,0,0,0},{0,0,0,0},{0,0,0,0},{0,0,0,0}};
#pragma unroll
        for (int t = 0; t < 4; t++) {
            d[t] = __builtin_amdgcn_mfma_f32_16x16x32_f16(a0, bWp[t][0], d[t], 0, 0, 0);
            d[t] = __builtin_amdgcn_mfma_f32_16x16x32_f16(a1, bWp[t][1], d[t], 0, 0, 0);
        }
#pragma unroll
        for (int t = 0; t < 4; t++)
#pragma unroll
            for (int r = 0; r < 4; r++) {
                int row = kg * 4 + r;
                float o = d[t][r];
                if (((r0 + row) % 9) == 0) o += bpv[t];
                stOut((OT*)&Yt[row][0], t * 16 + c16, o);
            }
        // coalesced copy: 16B chunks over lanes
        const int CH = (64 * (int)sizeof(OT)) / 16;     // chunks per row (u16:8, f32:16)
#pragma unroll
        for (int j = 0; j < (16 * CH) / 64; j++) {
            int c = lane + 64 * j;
            int row = c / CH;
            int cc = (c % CH) * (16 / (int)sizeof(OT));
            *(uint4*)&out[(size_t)(r0 + row) * 64 + cc] = *(const uint4*)&Yt[row][cc];
        }
    }
}

__global__ __launch_bounds__(256) void k7m_proj(
    const float* ns, const void* Wp, const void* bp, void* out, const int* flag)
{
    __shared__ __align__(16) unsigned char Ybuf[4][16 * 72 * 4];   // 18.4 KB (max f32 tile)
    const int wv = threadIdx.x >> 6;
    if (*flag) k7m_body<BF16, unsigned short>(ns, (const BF16*)Wp, (const BF16*)bp,
                               (unsigned short*)out, (unsigned short (*)[72])Ybuf[wv]);
    else       k7m_body<float, float>(ns, (const float*)Wp, (const float*)bp,
                               (float*)out, (float (*)[72])Ybuf[wv]);
}

extern "C" void kernel_launch(void* const* d_in, const int* in_sizes, int n_in,
                              void* d_out, int out_size, void* d_ws, size_t ws_size,
                              hipStream_t stream) {
    const void* node_input = d_in[0];
    const void* edge_attr  = d_in[1];
    const void* edge_scal  = d_in[2];
    const void* W_src      = d_in[3];
    const void* b_src      = d_in[4];
    const void* W_dst      = d_in[5];
    const void* rad_W1     = d_in[6];
    const void* rad_b1     = d_in[7];
    const void* rad_ln_g   = d_in[8];
    const void* rad_ln_b   = d_in[9];
    const void* rad_W2     = d_in[10];
    const void* rad_off    = d_in[11];
    const void* W_alpha    = d_in[12];
    const void* b_alpha    = d_in[13];
    const void* alpha_dot  = d_in[14];
    const void* W_value    = d_in[15];
    const void* b_value    = d_in[16];
    const void* W_proj     = d_in[17];
    const void* b_proj     = d_in[18];
    const int* edge_src    = (const int*)d_in[19];
    const int* edge_dst    = (const int*)d_in[20];

    char* ws = (char*)d_ws;
    size_t ofs = 0;
    auto alloc = [&](size_t bytes) -> char* {
        char* r = ws + ofs;
        ofs = (ofs + bytes + 255) & ~(size_t)255;
        return r;
    };

    int* flag       = (int*)alloc(256);
    int* cnt        = (int*)alloc((size_t)NN * 4);
    int* offs       = (int*)alloc((size_t)(NN + 16) * 4);
    int* cur        = (int*)alloc((size_t)NN * 4);
    int* csr        = (int*)alloc((size_t)NE * 4);
    unsigned* mseg  = (unsigned*)alloc((size_t)NN * 8 * 4);    //  0.32 MB
    float* sseg     = (float*)alloc((size_t)NN * 8 * 4);       //  0.32 MB
    float* alpha    = (float*)alloc((size_t)NE * 8 * 4);       //  5.12 MB
    _Float16* fs    = (_Float16*)alloc((size_t)NN * 576 * 2);  // 11.52 MB
    _Float16* fd    = (_Float16*)alloc((size_t)NN * 576 * 2);  // 11.52 MB
    _Float16* wlc   = (_Float16*)alloc((size_t)NE * 192 * 2);  // 61.44 MB
    float* nsum32   = (float*)alloc((size_t)NN * 576 * 4);     // 23.04 MB -> total ~115 MB

    // k0 also probes dtype (block 0 sole flag writer)
    k0_zero<<<dim3(625), dim3(256), 0, stream>>>(cnt, csr, flag, nsum32, mseg, sseg,
                                                 (const unsigned short*)node_input);
    // MFMA node feats: 5625 tiles over 1408 blocks x 4 waves
    k1m_feats<<<dim3(1408), dim3(256), 0, stream>>>(node_input, W_src, b_src, W_dst, fs, fd, flag);
    k2a_count<<<dim3(512), dim3(256), 0, stream>>>(edge_dst, cnt);
    k2b_scan<<<dim3(1), dim3(1024), 0, stream>>>(cnt, offs, cur);
    k2c_fill<<<dim3(512), dim3(256), 0, stream>>>(edge_dst, cur, csr);
    // MFMA radial MLP: 10000 tiles over 512 blocks x 4 waves (~5 tiles/wave)
    k3m_wlc<<<dim3(512), dim3(256), 0, stream>>>(edge_scal, rad_W1, rad_b1, rad_ln_g, rad_ln_b,
                                                 rad_W2, rad_off, wlc, flag);
    // MFMA alpha logits: 10000 tiles over 2500 blocks x 4 waves
    k4m_alpha<<<dim3(2500), dim3(256), 0, stream>>>(edge_attr, fs, fd, wlc, W_alpha, b_alpha,
                                                    alpha_dot, edge_src, edge_dst, alpha, mseg, flag);
    k5b_expsum<<<dim3(5000), dim3(256), 0, stream>>>(edge_dst, mseg, alpha, sseg);
    // 4 nodes per wave: 1250 blocks x 4 waves = 5000 waves (B-frag prologue amortized 4x)
    k6m_fused<<<dim3(1250), dim3(256), 0, stream>>>(offs, csr, edge_src, edge_attr, fs, fd, wlc,
                                                    W_value, b_value, alpha, sseg, nsum32, flag);
    // MFMA projection: 5625 tiles over 1408 blocks x 4 waves
    k7m_proj<<<dim3(1408), dim3(256), 0, stream>>>(nsum32, W_proj, b_proj, d_out, flag);
}

// Round 12
// 446.392 us; speedup vs baseline: 1.0797x; 1.0797x over previous
//
#include <hip/hip_runtime.h>
#include <stdint.h>

#define NN 10000
#define NE 160000
// C=64, M=9, H=8, D=8, RH=64, WN=192

struct BF16 { unsigned short v; };
typedef _Float16 h2_t __attribute__((ext_vector_type(2)));
typedef _Float16 f16x8 __attribute__((ext_vector_type(8)));
typedef float f32x4 __attribute__((ext_vector_type(4)));

__device__ __forceinline__ float cvt(float x) { return x; }
__device__ __forceinline__ float cvt(BF16 x) {
    union { unsigned int i; float f; } u; u.i = ((unsigned int)x.v) << 16; return u.f;
}
__device__ __forceinline__ unsigned short f2b_us(float f) {
    union { float f; unsigned int i; } v; v.f = f;
    unsigned int x = v.i;
    unsigned int lsb = (x >> 16) & 1u;
    x += 0x7fffu + lsb;
    return (unsigned short)(x >> 16);
}
__device__ __forceinline__ float sigm(float x) { return 1.0f / (1.0f + __expf(-x)); }
__device__ __forceinline__ int clampi(int v, int hi) { return (unsigned)v >= (unsigned)hi ? 0 : v; }

__device__ __forceinline__ void stOut(float* p, size_t i, float v) { p[i] = v; }
__device__ __forceinline__ void stOut(unsigned short* p, size_t i, float v) { p[i] = f2b_us(v); }

// ordered-uint encoding for float atomicMax
__device__ __forceinline__ unsigned okey(float f) {
    unsigned b = __float_as_uint(f);
    return (b & 0x80000000u) ? ~b : (b | 0x80000000u);
}
__device__ __forceinline__ float okdec(unsigned k) {
    unsigned b = (k & 0x80000000u) ? (k ^ 0x80000000u) : ~k;
    return __uint_as_float(b);
}

// 8 consecutive elements of T -> f16x8 (vector loads)
__device__ __forceinline__ f16x8 ld8f16(const BF16* p) {
    uint4 v = *(const uint4*)p;
    unsigned w0 = v.x, w1 = v.y, w2 = v.z, w3 = v.w;
    f16x8 r;
    union { unsigned u; float f; } c;
    c.u = (w0 & 0xFFFFu) << 16;  r[0] = (_Float16)c.f;
    c.u = (w0 & 0xFFFF0000u);    r[1] = (_Float16)c.f;
    c.u = (w1 & 0xFFFFu) << 16;  r[2] = (_Float16)c.f;
    c.u = (w1 & 0xFFFF0000u);    r[3] = (_Float16)c.f;
    c.u = (w2 & 0xFFFFu) << 16;  r[4] = (_Float16)c.f;
    c.u = (w2 & 0xFFFF0000u);    r[5] = (_Float16)c.f;
    c.u = (w3 & 0xFFFFu) << 16;  r[6] = (_Float16)c.f;
    c.u = (w3 & 0xFFFF0000u);    r[7] = (_Float16)c.f;
    return r;
}
__device__ __forceinline__ f16x8 ld8f16(const float* p) {
    float4 a = *(const float4*)p;
    float4 b = *(const float4*)(p + 4);
    f16x8 r;
    r[0] = (_Float16)a.x; r[1] = (_Float16)a.y; r[2] = (_Float16)a.z; r[3] = (_Float16)a.w;
    r[4] = (_Float16)b.x; r[5] = (_Float16)b.y; r[6] = (_Float16)b.z; r[7] = (_Float16)b.w;
    return r;
}

// ---------------- K0: zero cnt + csr + nsum32 + mseg + sseg, probe dtype, set flag ----------------
// Block 0 is the sole flag writer.
__global__ void k0_zero(int* __restrict__ cnt, int* __restrict__ csr, int* __restrict__ flag,
                        float* __restrict__ nsum, unsigned* __restrict__ mseg,
                        float* __restrict__ sseg, const unsigned short* __restrict__ x) {
    int i = blockIdx.x * blockDim.x + threadIdx.x;
    if (blockIdx.x == 0) {
        __shared__ int sbad[256];
        int bad = 0;
        for (int j = threadIdx.x; j < 16384; j += blockDim.x) {
            unsigned e = (x[j] >> 7) & 0xFFu;
            bad += (e == 0xFFu);
        }
        sbad[threadIdx.x] = bad;
        __syncthreads();
        for (int o = 128; o >= 1; o >>= 1) {
            if (threadIdx.x < o) sbad[threadIdx.x] += sbad[threadIdx.x + o];
            __syncthreads();
        }
        if (threadIdx.x == 0) *flag = (sbad[0] > 0) ? 0 : 1;
    }
    if (i < NN) cnt[i] = 0;
    if (i < NE) csr[i] = 0;
    if (i < NN * 8) { mseg[i] = 0u; sseg[i] = 0.f; }
    for (int j = i; j < NN * 576; j += gridDim.x * blockDim.x) nsum[j] = 0.f;
}

// ---------------- K1m: MFMA node feats -> fs, fd ----------------
template<typename T>
__device__ void k1m_body(const T* x, const T* Ws, const T* bs, const T* Wd,
                         _Float16* fs, _Float16* fd, _Float16 (*Yt)[128])
{
    const int lane = threadIdx.x & 63;
    const int c16 = lane & 15;
    const int kg  = lane >> 4;

    f16x8 bWs[4][2], bWd[4][2];
#pragma unroll
    for (int t = 0; t < 4; t++)
#pragma unroll
        for (int kh = 0; kh < 2; kh++) {
            f16x8 f1, f2;
#pragma unroll
            for (int j = 0; j < 8; j++) {
                int k = kh * 32 + kg * 8 + j;
                f1[j] = (_Float16)cvt(Ws[(size_t)k * 64 + t * 16 + c16]);
                f2[j] = (_Float16)cvt(Wd[(size_t)k * 64 + t * 16 + c16]);
            }
            bWs[t][kh] = f1; bWd[t][kh] = f2;
        }
    float bsv[4];
#pragma unroll
    for (int t = 0; t < 4; t++) bsv[t] = cvt(bs[t * 16 + c16]);

    const int NT = (NN * 9) / 16;   // 5625 exact
    for (int tile = blockIdx.x * 4 + (threadIdx.x >> 6); tile < NT; tile += gridDim.x * 4) {
        const int r0 = tile * 16;
        f16x8 a0 = ld8f16(&x[(size_t)(r0 + c16) * 64 + kg * 8]);
        f16x8 a1 = ld8f16(&x[(size_t)(r0 + c16) * 64 + 32 + kg * 8]);
        f32x4 hs[4] = {{0,0,0,0},{0,0,0,0},{0,0,0,0},{0,0,0,0}};
        f32x4 hd[4] = {{0,0,0,0},{0,0,0,0},{0,0,0,0},{0,0,0,0}};
#pragma unroll
        for (int t = 0; t < 4; t++) {
            hs[t] = __builtin_amdgcn_mfma_f32_16x16x32_f16(a0, bWs[t][0], hs[t], 0, 0, 0);
            hs[t] = __builtin_amdgcn_mfma_f32_16x16x32_f16(a1, bWs[t][1], hs[t], 0, 0, 0);
            hd[t] = __builtin_amdgcn_mfma_f32_16x16x32_f16(a0, bWd[t][0], hd[t], 0, 0, 0);
            hd[t] = __builtin_amdgcn_mfma_f32_16x16x32_f16(a1, bWd[t][1], hd[t], 0, 0, 0);
        }
#pragma unroll
        for (int t = 0; t < 4; t++)
#pragma unroll
            for (int r = 0; r < 4; r++) {
                int row = kg * 4 + r;
                float vs = hs[t][r];
                if (((r0 + row) % 9) == 0) vs += bsv[t];
                Yt[row][t * 16 + c16] = (_Float16)vs;
                Yt[row][64 + t * 16 + c16] = (_Float16)hd[t][r];
            }
#pragma unroll
        for (int j = 0; j < 2; j++) {
            int c = lane + 64 * j;      // chunk 0..127
            int row = c >> 3;
            int cc = (c & 7) * 8;
            *(f16x8*)&fs[(size_t)(r0 + row) * 64 + cc] = *(const f16x8*)&Yt[row][cc];
            *(f16x8*)&fd[(size_t)(r0 + row) * 64 + cc] = *(const f16x8*)&Yt[row][64 + cc];
        }
    }
}

__global__ __launch_bounds__(256) void k1m_feats(
    const void* x, const void* Ws, const void* bs, const void* Wd,
    _Float16* fs, _Float16* fd, const int* flag)
{
    __shared__ _Float16 Y[4][16][128];   // 16 KB
    const int wv = threadIdx.x >> 6;
    if (*flag) k1m_body<BF16>((const BF16*)x, (const BF16*)Ws, (const BF16*)bs, (const BF16*)Wd,
                              fs, fd, Y[wv]);
    else       k1m_body<float>((const float*)x, (const float*)Ws, (const float*)bs, (const float*)Wd,
                               fs, fd, Y[wv]);
}

// ---------------- K2: CSR build + permuted edge data ----------------
__global__ void k2a_count(const int* __restrict__ dst, int* __restrict__ cnt) {
    for (int e = blockIdx.x * blockDim.x + threadIdx.x; e < NE; e += gridDim.x * blockDim.x)
        atomicAdd(&cnt[clampi(dst[e], NN)], 1);
}

__global__ __launch_bounds__(1024) void k2b_scan(const int* __restrict__ cnt,
                                                 int* __restrict__ off, int* __restrict__ cur) {
    __shared__ int part[1024];
    int t = threadIdx.x;
    int base = t * 10;
    int loc[10]; int s = 0;
#pragma unroll
    for (int k = 0; k < 10; k++) { int i = base + k; int v = (i < NN) ? cnt[i] : 0; loc[k] = v; s += v; }
    part[t] = s; __syncthreads();
    for (int o = 1; o < 1024; o <<= 1) {
        int v = (t >= o) ? part[t - o] : 0;
        __syncthreads();
        part[t] += v;
        __syncthreads();
    }
    int run = (t == 0) ? 0 : part[t - 1];
#pragma unroll
    for (int k = 0; k < 10; k++) {
        int i = base + k;
        if (i < NN) { off[i] = run; cur[i] = run; run += loc[k]; }
    }
    if (t == 1023) off[NN] = part[1023];
}

// fills csr + CSR-ordered esrc/edst + ea rows (f16, padded to 16)
__global__ void k2c_fill(const int* __restrict__ dst, const int* __restrict__ src,
                         const void* __restrict__ ea, int* __restrict__ cur,
                         int* __restrict__ csr, int* __restrict__ esrcp,
                         int* __restrict__ edstp, _Float16* __restrict__ ea16,
                         const int* __restrict__ flag) {
    const int isbf = *flag;
    for (int e = blockIdx.x * blockDim.x + threadIdx.x; e < NE; e += gridDim.x * blockDim.x) {
        int d = clampi(dst[e], NN);
        int p = atomicAdd(&cur[d], 1);
        if ((unsigned)p < (unsigned)NE) {
            csr[p] = e;
            esrcp[p] = clampi(src[e], NN);
            edstp[p] = d;
            size_t bo = (size_t)p * 16;
            if (isbf) {
                const BF16* q = (const BF16*)ea + (size_t)e * 9;
#pragma unroll
                for (int m = 0; m < 9; m++) ea16[bo + m] = (_Float16)cvt(q[m]);
            } else {
                const float* q = (const float*)ea + (size_t)e * 9;
#pragma unroll
                for (int m = 0; m < 9; m++) ea16[bo + m] = (_Float16)q[m];
            }
#pragma unroll
            for (int m = 9; m < 16; m++) ea16[bo + m] = (_Float16)0.f;
        }
    }
}

// ---------------- K3m: MFMA radial MLP -> wlc f16 [slot q][3][64] (CSR-ordered) ----------------
// A rows gathered via csr[q]; output contiguous at q.
template<typename T>
__device__ void k3m_body(const T* es, const int* csr, const T* W1, const T* b1g, const T* gg,
                         const T* bbv, const T* W2, const T* roff, _Float16* wlc,
                         _Float16 (*Yt)[200])
{
    const int lane = threadIdx.x & 63;
    const int c16 = lane & 15;
    const int kg  = lane >> 4;

    f16x8 bW1[4][2], bW2[12][2];
#pragma unroll
    for (int t = 0; t < 4; t++)
#pragma unroll
        for (int kh = 0; kh < 2; kh++) {
            f16x8 f;
#pragma unroll
            for (int j = 0; j < 8; j++) {
                int k = kh * 32 + kg * 8 + j;
                f[j] = (_Float16)cvt(W1[(size_t)k * 64 + t * 16 + c16]);
            }
            bW1[t][kh] = f;
        }
#pragma unroll
    for (int t = 0; t < 12; t++)
#pragma unroll
        for (int kh = 0; kh < 2; kh++) {
            f16x8 f;
#pragma unroll
            for (int j = 0; j < 8; j++) {
                int k = kh * 32 + kg * 8 + j;
                f[j] = (_Float16)cvt(W2[(size_t)k * 192 + t * 16 + c16]);
            }
            bW2[t][kh] = f;
        }
    float b1v[4], gv[4], bv[4], rv[12];
#pragma unroll
    for (int t = 0; t < 4; t++) {
        b1v[t] = cvt(b1g[t * 16 + c16]);
        gv[t]  = cvt(gg[t * 16 + c16]);
        bv[t]  = cvt(bbv[t * 16 + c16]);
    }
#pragma unroll
    for (int t = 0; t < 12; t++) rv[t] = cvt(roff[t * 16 + c16]);

    const int NT = NE / 16;   // 10000 exact
    for (int tile = blockIdx.x * 4 + (threadIdx.x >> 6); tile < NT; tile += gridDim.x * 4) {
        const int q0 = tile * 16;
        const int eg = clampi(csr[q0 + c16], NE);     // gather source edge for this row
        f16x8 a0 = ld8f16(&es[(size_t)eg * 64 + kg * 8]);
        f16x8 a1 = ld8f16(&es[(size_t)eg * 64 + 32 + kg * 8]);
        f32x4 h[4] = {{0,0,0,0},{0,0,0,0},{0,0,0,0},{0,0,0,0}};
#pragma unroll
        for (int t = 0; t < 4; t++) {
            h[t] = __builtin_amdgcn_mfma_f32_16x16x32_f16(a0, bW1[t][0], h[t], 0, 0, 0);
            h[t] = __builtin_amdgcn_mfma_f32_16x16x32_f16(a1, bW1[t][1], h[t], 0, 0, 0);
        }
#pragma unroll
        for (int r = 0; r < 4; r++) {
            float x0 = h[0][r] + b1v[0], x1 = h[1][r] + b1v[1];
            float x2 = h[2][r] + b1v[2], x3 = h[3][r] + b1v[3];
            float s = x0 + x1 + x2 + x3;
            float q = x0 * x0 + x1 * x1 + x2 * x2 + x3 * x3;
            s += __shfl_xor(s, 1, 64); q += __shfl_xor(q, 1, 64);
            s += __shfl_xor(s, 2, 64); q += __shfl_xor(q, 2, 64);
            s += __shfl_xor(s, 4, 64); q += __shfl_xor(q, 4, 64);
            s += __shfl_xor(s, 8, 64); q += __shfl_xor(q, 8, 64);
            float mu = s * (1.0f / 64.0f);
            float var = fmaxf(q * (1.0f / 64.0f) - mu * mu, 0.0f);
            float rs = rsqrtf(var + 1e-5f);
            int row = kg * 4 + r;
#pragma unroll
            for (int t = 0; t < 4; t++) {
                float xt = (t == 0) ? x0 : (t == 1) ? x1 : (t == 2) ? x2 : x3;
                float v = (xt - mu) * rs * gv[t] + bv[t];
                v = v * sigm(v);
                Yt[row][t * 16 + c16] = (_Float16)v;
            }
        }
        f16x8 a20 = *(const f16x8*)&Yt[c16][kg * 8];
        f16x8 a21 = *(const f16x8*)&Yt[c16][32 + kg * 8];
        f32x4 y[12] = {{0,0,0,0},{0,0,0,0},{0,0,0,0},{0,0,0,0},{0,0,0,0},{0,0,0,0},
                       {0,0,0,0},{0,0,0,0},{0,0,0,0},{0,0,0,0},{0,0,0,0},{0,0,0,0}};
#pragma unroll
        for (int t = 0; t < 12; t++) {
            y[t] = __builtin_amdgcn_mfma_f32_16x16x32_f16(a20, bW2[t][0], y[t], 0, 0, 0);
            y[t] = __builtin_amdgcn_mfma_f32_16x16x32_f16(a21, bW2[t][1], y[t], 0, 0, 0);
        }
#pragma unroll
        for (int t = 0; t < 12; t++)
#pragma unroll
            for (int r = 0; r < 4; r++)
                Yt[kg * 4 + r][t * 16 + c16] = (_Float16)(y[t][r] + rv[t]);
#pragma unroll
        for (int j = 0; j < 6; j++) {
            int c = lane + 64 * j;
            int row = c / 24;
            int cc = (c % 24) * 8;
            *(f16x8*)&wlc[(size_t)(q0 + row) * 192 + cc] = *(const f16x8*)&Yt[row][cc];
        }
    }
}

__global__ __launch_bounds__(256) void k3m_wlc(
    const void* es, const int* csr, const void* W1, const void* b1, const void* g,
    const void* bln, const void* W2, const void* roff, _Float16* wlc, const int* flag)
{
    __shared__ _Float16 Y[4][16][200];   // 25.6 KB
    const int wv = threadIdx.x >> 6;
    if (*flag) k3m_body<BF16>((const BF16*)es, csr, (const BF16*)W1, (const BF16*)b1, (const BF16*)g,
                              (const BF16*)bln, (const BF16*)W2, (const BF16*)roff, wlc, Y[wv]);
    else       k3m_body<float>((const float*)es, csr, (const float*)W1, (const float*)b1, (const float*)g,
                               (const float*)bln, (const float*)W2, (const float*)roff, wlc, Y[wv]);
}

// ---------------- K4m: MFMA alpha logits + segment atomicMax (CSR-ordered) ----------------
template<typename T>
__device__ void k4m_body(const _Float16* ea16, const _Float16* fs, const _Float16* fd,
                         const _Float16* wlc, const T* Wa, const T* ba, const T* adot,
                         const int* esrcp, const int* edstp, float* alpha, unsigned* mseg,
                         float (*aS)[8])
{
    const int lane = threadIdx.x & 63;
    const int c16 = lane & 15;
    const int kgr = lane >> 4;

    f16x8 bWa[4][2];
#pragma unroll
    for (int t = 0; t < 4; t++)
#pragma unroll
        for (int kh = 0; kh < 2; kh++) {
            f16x8 f;
#pragma unroll
            for (int j = 0; j < 8; j++) {
                int k = kh * 32 + kgr * 8 + j;
                f[j] = (_Float16)cvt(Wa[(size_t)k * 64 + t * 16 + c16]);
            }
            bWa[t][kh] = f;
        }
    float bav[4], adv[4];
#pragma unroll
    for (int t = 0; t < 4; t++) {
        bav[t] = cvt(ba[t * 16 + c16]);
        adv[t] = cvt(adot[t * 16 + c16]);
    }

    const int NT = NE / 16;   // 10000 exact
    for (int tile = blockIdx.x * 4 + (threadIdx.x >> 6); tile < NT; tile += gridDim.x * 4) {
        const int q0 = tile * 16;
        const int qA = q0 + c16;
        const int sn = esrcp[qA];           // contiguous
        const int dn = edstp[qA];           // contiguous, nearly-constant per tile
        f16x8 fs0 = *(const f16x8*)&fs[(size_t)sn * 576 + kgr * 8];
        f16x8 fs1 = *(const f16x8*)&fs[(size_t)sn * 576 + 32 + kgr * 8];
        f16x8 fd0 = *(const f16x8*)&fd[(size_t)dn * 576 + kgr * 8];
        f16x8 fd1 = *(const f16x8*)&fd[(size_t)dn * 576 + 32 + kgr * 8];
        f16x8 wl0 = *(const f16x8*)&wlc[(size_t)qA * 192 + kgr * 8];
        f16x8 wl1 = *(const f16x8*)&wlc[(size_t)qA * 192 + 32 + kgr * 8];
        _Float16 eh = ea16[(size_t)qA * 16];
        f16x8 ev;
#pragma unroll
        for (int j = 0; j < 8; j++) ev[j] = eh;
        f16x8 a0 = (fs0 + fd0) * ev * wl0;
        f16x8 a1 = (fs1 + fd1) * ev * wl1;

        f32x4 d[4] = {{0,0,0,0},{0,0,0,0},{0,0,0,0},{0,0,0,0}};
#pragma unroll
        for (int t = 0; t < 4; t++) {
            d[t] = __builtin_amdgcn_mfma_f32_16x16x32_f16(a0, bWa[t][0], d[t], 0, 0, 0);
            d[t] = __builtin_amdgcn_mfma_f32_16x16x32_f16(a1, bWa[t][1], d[t], 0, 0, 0);
        }
#pragma unroll
        for (int t = 0; t < 4; t++)
#pragma unroll
            for (int r = 0; r < 4; r++) {
                float aw = d[t][r] + bav[t];
                float f = aw * (0.2f + 0.8f * sigm(aw));   // smooth_lrelu
                float p = f * adv[t];
                p += __shfl_xor(p, 1, 64);
                p += __shfl_xor(p, 2, 64);
                p += __shfl_xor(p, 4, 64);
                if ((c16 & 7) == 0)
                    aS[kgr * 4 + r][t * 2 + (c16 >> 3)] = p;
            }
        // coalesced alpha store + distributed atomicMax (2 entries/lane)
#pragma unroll
        for (int j = 0; j < 2; j++) {
            int idx = lane * 2 + j;       // 0..127
            int row = idx >> 3, h = idx & 7;
            float p = aS[row][h];
            alpha[(size_t)(q0 + row) * 8 + h] = p;
            int dnr = edstp[q0 + row];
            atomicMax(&mseg[dnr * 8 + h], okey(p));
        }
    }
}

__global__ __launch_bounds__(256) void k4m_alpha(
    const _Float16* ea16, const _Float16* fs, const _Float16* fd, const _Float16* wlc,
    const void* Wa, const void* ba, const void* adot,
    const int* esrcp, const int* edstp, float* alpha, unsigned* mseg, const int* flag)
{
    __shared__ float A[4][16][8];   // 2 KB
    const int wv = threadIdx.x >> 6;
    if (*flag) k4m_body<BF16>(ea16, fs, fd, wlc, (const BF16*)Wa, (const BF16*)ba,
                              (const BF16*)adot, esrcp, edstp, alpha, mseg, A[wv]);
    else       k4m_body<float>(ea16, fs, fd, wlc, (const float*)Wa, (const float*)ba,
                               (const float*)adot, esrcp, edstp, alpha, mseg, A[wv]);
}

// ---------------- K5b: edge-parallel exp + segment sum (CSR-ordered) ----------------
__global__ void k5b_expsum(const int* __restrict__ edstp, const unsigned* __restrict__ mseg,
                           float* __restrict__ alpha, float* __restrict__ sseg) {
    int t = blockIdx.x * blockDim.x + threadIdx.x;
    if (t >= NE * 8) return;
    int q = t >> 3, h = t & 7;
    int dn = clampi(edstp[q], NN);
    float m = okdec(mseg[dn * 8 + h]);
    float ex = __expf(alpha[t] - m);
    alpha[t] = ex;
    unsafeAtomicAdd(&sseg[dn * 8 + h], ex);
}

// ---------------- K6m v2.2: MFMA msg+value+gate+cp_tp, 2 waves/node, LDS staging ----------------
// All per-edge data (esrcp, wlc, ea16, alpha) CSR-ordered -> coalesced; only fs[src] gathers remain.
template<typename T>
__device__ void k6m_body(const int* off, const int* esrcp,
                         const _Float16* ea16, const _Float16* fs, const _Float16* fd,
                         const _Float16* wlc, const T* Wv, const T* bv,
                         const float* alpha, const float* sseg, float* nsum,
                         _Float16 (*wlS)[16][72], float (*mtS)[20])
{
    const int lane = threadIdx.x & 63;
    const int wvid = threadIdx.x >> 6;
    const int c16 = lane & 15;     // A row / D col (within 16-tile)
    const int kg  = lane >> 4;     // k-group & D row-group

    const int gw  = blockIdx.x * 4 + wvid;   // exact: 4*gridDim == NN*2
    const int n = gw >> 1;
    const int half = gw & 1;
    const int b = off[n], e_end = off[n + 1];
    if (b >= e_end) return;

    // ---- B fragments for this wave's two 16-col tiles ----
    f16x8 bfV[2][2], bfG[2][2];
    float bvv[2], bgv[2];
    int colg[2], hh[2];
    float invs[2];
#pragma unroll
    for (int t = 0; t < 2; t++) {
        colg[t] = (half * 2 + t) * 16 + c16;
        hh[t] = colg[t] >> 3;
        invs[t] = 1.0f / (sseg[n * 8 + hh[t]] + 1e-16f);
#pragma unroll
        for (int kh = 0; kh < 2; kh++) {
            f16x8 b8v, b8g;
#pragma unroll
            for (int j = 0; j < 8; j++) {
                int k = kh * 32 + kg * 8 + j;
                b8v[j] = (_Float16)cvt(Wv[(size_t)k * 128 + colg[t]]);
                b8g[j] = (_Float16)cvt(Wv[(size_t)k * 128 + 64 + colg[t]]);
            }
            bfV[t][kh] = b8v; bfG[t][kh] = b8g;
        }
        bvv[t] = cvt(bv[colg[t]]);
        bgv[t] = cvt(bv[64 + colg[t]]);
    }

    const size_t fdb = (size_t)n * 576;
    const size_t nbase = (size_t)n * 576;

    for (int p0 = b; p0 < e_end; p0 += 16) {
        int pA = p0 + c16; if (pA >= e_end) pA = e_end - 1;
        const int snA = esrcp[pA];                 // coalesced
        const size_t fsb = (size_t)snA * 576;
        const size_t wlb = (size_t)pA * 192;       // coalesced rows

        // ---- stage wl rows (raw f16), ea row, alpha row into LDS ----
#pragma unroll
        for (int l = 0; l < 3; l++)
#pragma unroll
            for (int kh = 0; kh < 2; kh++)
                *(f16x8*)&wlS[l][c16][kh * 32 + kg * 8] =
                    *(const f16x8*)&wlc[wlb + (size_t)l * 64 + kh * 32 + kg * 8];
        float eao[9];
        {
            f16x8 ep0 = *(const f16x8*)&ea16[(size_t)pA * 16];
            _Float16 e8 = ea16[(size_t)pA * 16 + 8];
#pragma unroll
            for (int m = 0; m < 8; m++) eao[m] = (float)ep0[m];
            eao[8] = (float)e8;
        }
        if (kg == 0) {
#pragma unroll
            for (int m = 0; m < 9; m++) mtS[c16][m] = eao[m];
        }
        mtS[c16][10 + kg * 2]     = alpha[(size_t)pA * 8 + kg * 2];
        mtS[c16][10 + kg * 2 + 1] = alpha[(size_t)pA * 8 + kg * 2 + 1];

        // per-epilogue-row alpha * invs * validity (m-independent)
        float awm[2][4];
#pragma unroll
        for (int r = 0; r < 4; r++) {
            int row = kg * 4 + r;
            float vm = (p0 + row < e_end) ? 1.f : 0.f;
#pragma unroll
            for (int t = 0; t < 2; t++)
                awm[t][r] = mtS[row][10 + hh[t]] * invs[t] * vm;
        }

        float gtv[2][4];
        // ---------- m = 0: value + gate ----------
        {
            f16x8 a0, a1;
            {
                f16x8 w0 = *(const f16x8*)&wlS[0][c16][kg * 8];
                f16x8 w1 = *(const f16x8*)&wlS[0][c16][32 + kg * 8];
                f16x8 fd0 = *(const f16x8*)&fd[fdb + kg * 8];
                f16x8 fd1 = *(const f16x8*)&fd[fdb + 32 + kg * 8];
                f16x8 fs0 = *(const f16x8*)&fs[fsb + kg * 8];
                f16x8 fs1 = *(const f16x8*)&fs[fsb + 32 + kg * 8];
                _Float16 eh = (_Float16)eao[0];
                f16x8 ev;
#pragma unroll
                for (int j = 0; j < 8; j++) ev[j] = eh;
                a0 = (fs0 + fd0) * ev * w0;
                a1 = (fs1 + fd1) * ev * w1;
            }
            f32x4 d[2] = {{0,0,0,0},{0,0,0,0}};
            f32x4 g[2] = {{0,0,0,0},{0,0,0,0}};
#pragma unroll
            for (int t = 0; t < 2; t++) {
                d[t] = __builtin_amdgcn_mfma_f32_16x16x32_f16(a0, bfV[t][0], d[t], 0, 0, 0);
                d[t] = __builtin_amdgcn_mfma_f32_16x16x32_f16(a1, bfV[t][1], d[t], 0, 0, 0);
                g[t] = __builtin_amdgcn_mfma_f32_16x16x32_f16(a0, bfG[t][0], g[t], 0, 0, 0);
                g[t] = __builtin_amdgcn_mfma_f32_16x16x32_f16(a1, bfG[t][1], g[t], 0, 0, 0);
            }
#pragma unroll
            for (int t = 0; t < 2; t++) {
                float ps = 0.f;
#pragma unroll
                for (int r = 0; r < 4; r++) {
                    int row = kg * 4 + r;
                    gtv[t][r] = sigm(g[t][r] + bgv[t]);
                    float v = d[t][r] + bvv[t];
                    float f = v * sigm(v);
                    float wlv = (float)wlS[0][row][colg[t]];
                    float eam = mtS[row][0];
                    ps = fmaf(f * (eam * wlv), awm[t][r], ps);
                }
                ps += __shfl_xor(ps, 16, 64);
                ps += __shfl_xor(ps, 32, 64);
                if (kg == 0) unsafeAtomicAdd(&nsum[nbase + colg[t]], ps);
            }
        }
        // ---------- m = 1..8: value * gate ----------
#pragma unroll 2
        for (int m = 1; m < 9; m++) {
            const int l = (m < 4) ? 1 : 2;
            f16x8 a0, a1;
            {
                const size_t mo = (size_t)m * 64;
                f16x8 w0 = *(const f16x8*)&wlS[l][c16][kg * 8];
                f16x8 w1 = *(const f16x8*)&wlS[l][c16][32 + kg * 8];
                f16x8 fd0 = *(const f16x8*)&fd[fdb + mo + kg * 8];
                f16x8 fd1 = *(const f16x8*)&fd[fdb + mo + 32 + kg * 8];
                f16x8 fs0 = *(const f16x8*)&fs[fsb + mo + kg * 8];
                f16x8 fs1 = *(const f16x8*)&fs[fsb + mo + 32 + kg * 8];
                _Float16 eh = (_Float16)eao[m];
                f16x8 ev;
#pragma unroll
                for (int j = 0; j < 8; j++) ev[j] = eh;
                a0 = (fs0 + fd0) * ev * w0;
                a1 = (fs1 + fd1) * ev * w1;
            }
            f32x4 d[2] = {{0,0,0,0},{0,0,0,0}};
#pragma unroll
            for (int t = 0; t < 2; t++) {
                d[t] = __builtin_amdgcn_mfma_f32_16x16x32_f16(a0, bfV[t][0], d[t], 0, 0, 0);
                d[t] = __builtin_amdgcn_mfma_f32_16x16x32_f16(a1, bfV[t][1], d[t], 0, 0, 0);
            }
#pragma unroll
            for (int t = 0; t < 2; t++) {
                float ps = 0.f;
#pragma unroll
                for (int r = 0; r < 4; r++) {
                    int row = kg * 4 + r;
                    float f = d[t][r] * gtv[t][r];
                    float wlv = (float)wlS[l][row][colg[t]];
                    float eam = mtS[row][m];
                    ps = fmaf(f * (eam * wlv), awm[t][r], ps);
                }
                ps += __shfl_xor(ps, 16, 64);
                ps += __shfl_xor(ps, 32, 64);
                if (kg == 0) unsafeAtomicAdd(&nsum[nbase + (size_t)m * 64 + colg[t]], ps);
            }
        }
    }
}

__global__ __launch_bounds__(256) void k6m_fused(
    const int* off, const int* esrcp,
    const _Float16* ea16, const _Float16* fs, const _Float16* fd, const _Float16* wlc,
    const void* Wv, const void* bv,
    const float* alpha, const float* sseg, float* nsum, const int* flag)
{
    __shared__ _Float16 shwl[4][3][16][72];   // 27.0 KB
    __shared__ float    shmt[4][16][20];      //  5.0 KB
    const int wvid = threadIdx.x >> 6;
    if (*flag) k6m_body<BF16>(off, esrcp, ea16, fs, fd, wlc,
                              (const BF16*)Wv, (const BF16*)bv, alpha, sseg, nsum,
                              shwl[wvid], shmt[wvid]);
    else       k6m_body<float>(off, esrcp, ea16, fs, fd, wlc,
                               (const float*)Wv, (const float*)bv, alpha, sseg, nsum,
                               shwl[wvid], shmt[wvid]);
}

// ---------------- K7m: MFMA output projection (f32 nsum -> out) ----------------
template<typename T, typename OT>
__device__ void k7m_body(const float* ns, const T* Wp, const T* bp, OT* out, OT (*Yt)[72])
{
    const int lane = threadIdx.x & 63;
    const int c16 = lane & 15;
    const int kg  = lane >> 4;

    f16x8 bWp[4][2];
#pragma unroll
    for (int t = 0; t < 4; t++)
#pragma unroll
        for (int kh = 0; kh < 2; kh++) {
            f16x8 f;
#pragma unroll
            for (int j = 0; j < 8; j++) {
                int k = kh * 32 + kg * 8 + j;
                f[j] = (_Float16)cvt(Wp[(size_t)k * 64 + t * 16 + c16]);
            }
            bWp[t][kh] = f;
        }
    float bpv[4];
#pragma unroll
    for (int t = 0; t < 4; t++) bpv[t] = cvt(bp[t * 16 + c16]);

    const int NT = (NN * 9) / 16;   // 5625 exact
    for (int tile = blockIdx.x * 4 + (threadIdx.x >> 6); tile < NT; tile += gridDim.x * 4) {
        const int r0 = tile * 16;
        f16x8 a0 = ld8f16(&ns[(size_t)(r0 + c16) * 64 + kg * 8]);
        f16x8 a1 = ld8f16(&ns[(size_t)(r0 + c16) * 64 + 32 + kg * 8]);
        f32x4 d[4] = {{0,0,0,0},{0,0,0,0},{0,0,0,0},{0,0,0,0}};
#pragma unroll
        for (int t = 0; t < 4; t++) {
            d[t] = __builtin_amdgcn_mfma_f32_16x16x32_f16(a0, bWp[t][0], d[t], 0, 0, 0);
            d[t] = __builtin_amdgcn_mfma_f32_16x16x32_f16(a1, bWp[t][1], d[t], 0, 0, 0);
        }
#pragma unroll
        for (int t = 0; t < 4; t++)
#pragma unroll
            for (int r = 0; r < 4; r++) {
                int row = kg * 4 + r;
                float o = d[t][r];
                if (((r0 + row) % 9) == 0) o += bpv[t];
                stOut((OT*)&Yt[row][0], t * 16 + c16, o);
            }
        // coalesced copy: 16B chunks over lanes
        const int CH = (64 * (int)sizeof(OT)) / 16;     // chunks per row (u16:8, f32:16)
#pragma unroll
        for (int j = 0; j < (16 * CH) / 64; j++) {
            int c = lane + 64 * j;
            int row = c / CH;
            int cc = (c % CH) * (16 / (int)sizeof(OT));
            *(uint4*)&out[(size_t)(r0 + row) * 64 + cc] = *(const uint4*)&Yt[row][cc];
        }
    }
}

__global__ __launch_bounds__(256) void k7m_proj(
    const float* ns, const void* Wp, const void* bp, void* out, const int* flag)
{
    __shared__ __align__(16) unsigned char Ybuf[4][16 * 72 * 4];   // 18.4 KB (max f32 tile)
    const int wv = threadIdx.x >> 6;
    if (*flag) k7m_body<BF16, unsigned short>(ns, (const BF16*)Wp, (const BF16*)bp,
                               (unsigned short*)out, (unsigned short (*)[72])Ybuf[wv]);
    else       k7m_body<float, float>(ns, (const float*)Wp, (const float*)bp,
                               (float*)out, (float (*)[72])Ybuf[wv]);
}

extern "C" void kernel_launch(void* const* d_in, const int* in_sizes, int n_in,
                              void* d_out, int out_size, void* d_ws, size_t ws_size,
                              hipStream_t stream) {
    const void* node_input = d_in[0];
    const void* edge_attr  = d_in[1];
    const void* edge_scal  = d_in[2];
    const void* W_src      = d_in[3];
    const void* b_src      = d_in[4];
    const void* W_dst      = d_in[5];
    const void* rad_W1     = d_in[6];
    const void* rad_b1     = d_in[7];
    const void* rad_ln_g   = d_in[8];
    const void* rad_ln_b   = d_in[9];
    const void* rad_W2     = d_in[10];
    const void* rad_off    = d_in[11];
    const void* W_alpha    = d_in[12];
    const void* b_alpha    = d_in[13];
    const void* alpha_dot  = d_in[14];
    const void* W_value    = d_in[15];
    const void* b_value    = d_in[16];
    const void* W_proj     = d_in[17];
    const void* b_proj     = d_in[18];
    const int* edge_src    = (const int*)d_in[19];
    const int* edge_dst    = (const int*)d_in[20];

    char* ws = (char*)d_ws;
    size_t ofs = 0;
    auto alloc = [&](size_t bytes) -> char* {
        char* r = ws + ofs;
        ofs = (ofs + bytes + 255) & ~(size_t)255;
        return r;
    };

    int* flag       = (int*)alloc(256);
    int* cnt        = (int*)alloc((size_t)NN * 4);
    int* offs       = (int*)alloc((size_t)(NN + 16) * 4);
    int* cur        = (int*)alloc((size_t)NN * 4);
    int* csr        = (int*)alloc((size_t)NE * 4);
    int* esrcp      = (int*)alloc((size_t)NE * 4);             //  0.64 MB
    int* edstp      = (int*)alloc((size_t)NE * 4);             //  0.64 MB
    unsigned* mseg  = (unsigned*)alloc((size_t)NN * 8 * 4);    //  0.32 MB
    float* sseg     = (float*)alloc((size_t)NN * 8 * 4);       //  0.32 MB
    float* alpha    = (float*)alloc((size_t)NE * 8 * 4);       //  5.12 MB
    _Float16* ea16  = (_Float16*)alloc((size_t)NE * 16 * 2);   //  5.12 MB
    _Float16* fs    = (_Float16*)alloc((size_t)NN * 576 * 2);  // 11.52 MB
    _Float16* fd    = (_Float16*)alloc((size_t)NN * 576 * 2);  // 11.52 MB
    _Float16* wlc   = (_Float16*)alloc((size_t)NE * 192 * 2);  // 61.44 MB
    float* nsum32   = (float*)alloc((size_t)NN * 576 * 4);     // 23.04 MB -> total ~121 MB

    // k0 also probes dtype (block 0 sole flag writer)
    k0_zero<<<dim3(625), dim3(256), 0, stream>>>(cnt, csr, flag, nsum32, mseg, sseg,
                                                 (const unsigned short*)node_input);
    // MFMA node feats: 5625 tiles over 1408 blocks x 4 waves
    k1m_feats<<<dim3(1408), dim3(256), 0, stream>>>(node_input, W_src, b_src, W_dst, fs, fd, flag);
    k2a_count<<<dim3(512), dim3(256), 0, stream>>>(edge_dst, cnt);
    k2b_scan<<<dim3(1), dim3(1024), 0, stream>>>(cnt, offs, cur);
    // CSR fill + permuted esrc/edst + f16 edge_attr rows
    k2c_fill<<<dim3(512), dim3(256), 0, stream>>>(edge_dst, edge_src, edge_attr, cur, csr,
                                                  esrcp, edstp, ea16, flag);
    // MFMA radial MLP, CSR-ordered output: 10000 tiles over 512 blocks x 4 waves
    k3m_wlc<<<dim3(512), dim3(256), 0, stream>>>(edge_scal, csr, rad_W1, rad_b1, rad_ln_g,
                                                 rad_ln_b, rad_W2, rad_off, wlc, flag);
    // MFMA alpha logits, CSR-ordered: 10000 tiles over 2500 blocks x 4 waves
    k4m_alpha<<<dim3(2500), dim3(256), 0, stream>>>(ea16, fs, fd, wlc, W_alpha, b_alpha,
                                                    alpha_dot, esrcp, edstp, alpha, mseg, flag);
    k5b_expsum<<<dim3(5000), dim3(256), 0, stream>>>(edstp, mseg, alpha, sseg);
    // 2 waves per node: 5000 blocks x 4 waves = 20000 waves (R10 grid; coalesced edge streams)
    k6m_fused<<<dim3(5000), dim3(256), 0, stream>>>(offs, esrcp, ea16, fs, fd, wlc,
                                                    W_value, b_value, alpha, sseg, nsum32, flag);
    // MFMA projection: 5625 tiles over 1408 blocks x 4 waves
    k7m_proj<<<dim3(1408), dim3(256), 0, stream>>>(nsum32, W_proj, b_proj, d_out, flag);
}